// Round 1
// baseline (152.541 us; speedup 1.0000x reference)
//
#include <hip/hip_runtime.h>

#define CTX_T 768
#define CDIM  1024
#define BDIM  8

typedef __attribute__((ext_vector_type(8))) __bf16 bf16x8;
typedef __attribute__((ext_vector_type(8))) short short8;
typedef __attribute__((ext_vector_type(4))) float f32x4;

__device__ inline unsigned short f2bf(float f) {
    union { float f; unsigned u; } v; v.f = f;
    unsigned r = v.u + 0x7fffu + ((v.u >> 16) & 1u);
    return (unsigned short)(r >> 16);
}

// ---- float32 -> bf16 raw-bits converter (n % 1024 == 0) ----
__global__ void cvt_f32_bf16(const float* __restrict__ s, unsigned short* __restrict__ d, int n) {
    int i = (blockIdx.x * blockDim.x + threadIdx.x) * 4;
    if (i >= n) return;
    float4 f = *(const float4*)(s + i);
    ushort4 o;
    o.x = f2bf(f.x); o.y = f2bf(f.y); o.z = f2bf(f.z); o.w = f2bf(f.w);
    *(ushort4*)(d + i) = o;
}

// ---- time-shift + mix, f32 in -> bf16 out ----
__global__ void mix_bf16(const float* __restrict__ x, const float* __restrict__ tm,
                         unsigned short* __restrict__ xm, int total) {
    int i = (blockIdx.x * blockDim.x + threadIdx.x) * 4;
    if (i >= total) return;
    int c  = i & (CDIM - 1);
    int bt = i >> 10;            // / CDIM
    int t  = bt % CTX_T;
    float4 xc  = *(const float4*)(x + i);
    float4 tmc = *(const float4*)(tm + c);
    float4 xp = make_float4(0.f, 0.f, 0.f, 0.f);
    if (t > 0) xp = *(const float4*)(x + i - CDIM);
    ushort4 o;
    o.x = f2bf(xc.x * tmc.x + xp.x * (1.f - tmc.x));
    o.y = f2bf(xc.y * tmc.y + xp.y * (1.f - tmc.y));
    o.z = f2bf(xc.z * tmc.z + xp.z * (1.f - tmc.z));
    o.w = f2bf(xc.w * tmc.w + xp.w * (1.f - tmc.w));
    *(ushort4*)(xm + i) = o;
}

// ---- bf16 MFMA GEMM: C[m,n] = sum_k A[m,k] * Bw[n,k]  (B^T form) ----
// 128x128 tile, BK=32, 4 waves (2x2), 64x64 per wave, 4x4 16x16x32 frags.
#define GLL16(GP, LP) __builtin_amdgcn_global_load_lds(                        \
    (__attribute__((address_space(1))) void*)(void*)(GP),                     \
    (__attribute__((address_space(3))) void*)(void*)(LP), 16, 0, 0)

__global__ __launch_bounds__(256) void gemm_bt(const unsigned short* __restrict__ A,
                                               const unsigned short* __restrict__ Bw,
                                               float* __restrict__ C,
                                               int N, int K) {
    __shared__ unsigned short lA[128 * 32];
    __shared__ unsigned short lB[128 * 32];
    const int tid  = threadIdx.x;
    const int lane = tid & 63;
    const int wid  = tid >> 6;
    const int wr   = wid >> 1, wc = wid & 1;
    const size_t m0 = (size_t)blockIdx.x * 128;
    const size_t n0 = (size_t)blockIdx.y * 128;

    const unsigned short* gA = A + (m0 + (size_t)(tid >> 2)) * K + ((tid & 3) << 3);
    const unsigned short* gB = Bw + (n0 + (size_t)(tid >> 2)) * K + ((tid & 3) << 3);
    char* sA = (char*)lA + tid * 16;
    char* sB = (char*)lB + tid * 16;

    f32x4 acc[4][4] = {};

    for (int k0 = 0; k0 < K; k0 += 32) {
        GLL16(gA + k0,             sA);
        GLL16(gA + k0 + 64 * K,    sA + 4096);
        GLL16(gB + k0,             sB);
        GLL16(gB + k0 + 64 * K,    sB + 4096);
        __syncthreads();

        const unsigned short* pA = lA + (wr * 64 + (lane & 15)) * 32 + ((lane >> 4) << 3);
        const unsigned short* pB = lB + (wc * 64 + (lane & 15)) * 32 + ((lane >> 4) << 3);
        bf16x8 a[4], b[4];
#pragma unroll
        for (int i = 0; i < 4; i++) {
            a[i] = __builtin_bit_cast(bf16x8, *(const short8*)(pA + i * 16 * 32));
            b[i] = __builtin_bit_cast(bf16x8, *(const short8*)(pB + i * 16 * 32));
        }
#pragma unroll
        for (int i = 0; i < 4; i++)
#pragma unroll
            for (int j = 0; j < 4; j++)
                acc[i][j] = __builtin_amdgcn_mfma_f32_16x16x32_bf16(a[i], b[j], acc[i][j], 0, 0, 0);
        __syncthreads();
    }

#pragma unroll
    for (int i = 0; i < 4; i++) {
#pragma unroll
        for (int j = 0; j < 4; j++) {
            size_t row = m0 + wr * 64 + i * 16 + ((lane >> 4) << 2);
            size_t col = n0 + wc * 64 + j * 16 + (lane & 15);
            float* Cp = C + row * (size_t)N + col;
#pragma unroll
            for (int q = 0; q < 4; q++) Cp[(size_t)q * N] = acc[i][j][q];
        }
    }
}

// ---- chunked WKV scan: 8 chunks x 32 channels per block ----
// state S(t) = exp(-ed)*S(t-1) + z[t]; wkv[t] = exp(tf)*kv[t] + S_kv(t-1); same for k.
__global__ __launch_bounds__(256) void wkv_scan(const float* __restrict__ KVR,
                                                const float* __restrict__ td,
                                                const float* __restrict__ tf,
                                                unsigned short* __restrict__ rwkv) {
    const int T = CTX_T, C = CDIM;
    const int CW = 32, CH = 8, L = T / CH;   // 96 steps/chunk
    int b  = blockIdx.x / (C / CW);
    int cb = blockIdx.x % (C / CW);
    int cl = threadIdx.x & (CW - 1);
    int j  = threadIdx.x / CW;               // chunk id
    int c  = cb * CW + cl;

    float ed    = expf(td[c]);
    float dec   = expf(-ed);
    float wself = expf(tf[c]);
    const float* base = KVR + (size_t)b * T * 3 * C + c;

    // phase 1: chunk-local scan (no incoming carry)
    float A = 0.f, Bs = 0.f;
#pragma unroll 4
    for (int i = 0; i < L; i++) {
        const float* p = base + (size_t)(j * L + i) * (3 * C);
        float kp = p[0];
        float vv = p[C];
        float kk = expf(fminf(kp, 60.f));
        A  = dec * A + kk * vv;
        Bs = dec * Bs + kk;
    }

    __shared__ float sA[CH][CW], sB[CH][CW];
    sA[j][cl] = A; sB[j][cl] = Bs;
    __syncthreads();

    // phase 2: serial carry propagation across the 8 chunks (32 threads)
    if (j == 0) {
        float dL = expf(-ed * (float)L);   // dec^L
        float cA = 0.f, cB = 0.f;
#pragma unroll
        for (int q = 0; q < CH; q++) {
            float tA = sA[q][cl], tB = sB[q][cl];
            sA[q][cl] = cA; sB[q][cl] = cB;   // carry INTO chunk q
            cA = dL * cA + tA;
            cB = dL * cB + tB;
        }
    }
    __syncthreads();
    A = sA[j][cl]; Bs = sB[j][cl];

    // phase 3: scan with carry, emit sigmoid(r) * wkv / wk as bf16
    unsigned short* outp = rwkv + (size_t)(b * T + j * L) * C + c;
#pragma unroll 4
    for (int i = 0; i < L; i++) {
        const float* p = base + (size_t)(j * L + i) * (3 * C);
        float kp = p[0], vv = p[C], rr = p[2 * C];
        float kk = expf(fminf(kp, 60.f));
        float kv = kk * vv;
        float wkv = wself * kv + A;
        float wk  = wself * kk + Bs + 1e-9f;
        float sg  = 1.f / (1.f + expf(-rr));
        outp[(size_t)i * C] = f2bf(sg * wkv / wk);
        A  = dec * A + kv;
        Bs = dec * Bs + kk;
    }
}

extern "C" void kernel_launch(void* const* d_in, const int* in_sizes, int n_in,
                              void* d_out, int out_size, void* d_ws, size_t ws_size,
                              hipStream_t stream) {
    const float* x  = (const float*)d_in[0];
    const float* td = (const float*)d_in[1];
    const float* tf = (const float*)d_in[2];
    const float* tm = (const float*)d_in[3];
    const float* Wk = (const float*)d_in[4];
    const float* Wv = (const float*)d_in[5];
    const float* Wr = (const float*)d_in[6];
    const float* Wo = (const float*)d_in[7];
    float* out = (float*)d_out;

    const int B = BDIM, T = CTX_T, C = CDIM;
    const size_t M = (size_t)B * T;   // 6144

    size_t off = 0;
    auto carve = [&](size_t bytes) -> void* {
        void* p = (char*)d_ws + off;
        off += (bytes + 255) & ~(size_t)255;
        return p;
    };
    unsigned short* xm   = (unsigned short*)carve(M * C * 2);            // bf16 mixed input
    unsigned short* wkvr = (unsigned short*)carve((size_t)3 * C * C * 2); // [3C][C] bf16 weights
    unsigned short* wo   = (unsigned short*)carve((size_t)C * C * 2);
    float*          kvr  = (float*)carve(M * 3 * C * 4);                 // [M][3C] f32 projections
    unsigned short* rwkv = (unsigned short*)carve(M * C * 2);            // bf16 gated output

    const int nW = C * C;   // 1M elems per weight matrix
    cvt_f32_bf16<<<nW / 4 / 256, 256, 0, stream>>>(Wk, wkvr,          nW);
    cvt_f32_bf16<<<nW / 4 / 256, 256, 0, stream>>>(Wv, wkvr + nW,     nW);
    cvt_f32_bf16<<<nW / 4 / 256, 256, 0, stream>>>(Wr, wkvr + 2 * nW, nW);
    cvt_f32_bf16<<<nW / 4 / 256, 256, 0, stream>>>(Wo, wo,            nW);

    const int total = (int)(M * C);
    mix_bf16<<<total / 4 / 256, 256, 0, stream>>>(x, tm, xm, total);

    dim3 g1((unsigned)(M / 128), (unsigned)(3 * C / 128));   // 48 x 24
    gemm_bt<<<g1, 256, 0, stream>>>(xm, wkvr, kvr, 3 * C, C);

    wkv_scan<<<B * (C / 32), 256, 0, stream>>>(kvr, td, tf, rwkv);

    dim3 g2((unsigned)(M / 128), (unsigned)(C / 128));       // 48 x 8
    gemm_bt<<<g2, 256, 0, stream>>>(rwkv, wo, out, C, C);
}

// Round 2
// 143.452 us; speedup vs baseline: 1.0634x; 1.0634x over previous
//
#include <hip/hip_runtime.h>

#define CTX_T 768
#define CDIM  1024
#define BDIM  8
#define MTOT  (BDIM * CTX_T)   // 6144

typedef __attribute__((ext_vector_type(8))) __bf16 bf16x8;
typedef __attribute__((ext_vector_type(8))) short short8;
typedef __attribute__((ext_vector_type(4))) float f32x4;

__device__ inline unsigned short f2bf(float f) {
    union { float f; unsigned u; } v; v.f = f;
    unsigned r = v.u + 0x7fffu + ((v.u >> 16) & 1u);
    return (unsigned short)(r >> 16);
}
__device__ inline float bf2f(unsigned short u) {
    union { unsigned u; float f; } v; v.u = ((unsigned)u) << 16; return v.f;
}

// ---- fused f32 -> bf16 converter for the 4 weight matrices (each 2^20 elems) ----
__global__ void cvt4(const float* __restrict__ s0, const float* __restrict__ s1,
                     const float* __restrict__ s2, const float* __restrict__ s3,
                     unsigned short* __restrict__ d) {
    int i = (blockIdx.x * blockDim.x + threadIdx.x) * 4;
    const int SEG = 1 << 20;
    const float* s = (i < SEG) ? s0 : (i < 2 * SEG) ? s1 : (i < 3 * SEG) ? s2 : s3;
    float4 f = *(const float4*)(s + (i & (SEG - 1)));
    ushort4 o;
    o.x = f2bf(f.x); o.y = f2bf(f.y); o.z = f2bf(f.z); o.w = f2bf(f.w);
    *(ushort4*)(d + i) = o;
}

// ---- time-shift + mix, f32 in -> bf16 out ----
__global__ void mix_bf16(const float* __restrict__ x, const float* __restrict__ tm,
                         unsigned short* __restrict__ xm, int total) {
    int i = (blockIdx.x * blockDim.x + threadIdx.x) * 4;
    if (i >= total) return;
    int c  = i & (CDIM - 1);
    int bt = i >> 10;
    int t  = bt % CTX_T;
    float4 xc  = *(const float4*)(x + i);
    float4 tmc = *(const float4*)(tm + c);
    float4 xp = make_float4(0.f, 0.f, 0.f, 0.f);
    if (t > 0) xp = *(const float4*)(x + i - CDIM);
    ushort4 o;
    o.x = f2bf(xc.x * tmc.x + xp.x * (1.f - tmc.x));
    o.y = f2bf(xc.y * tmc.y + xp.y * (1.f - tmc.y));
    o.z = f2bf(xc.z * tmc.z + xp.z * (1.f - tmc.z));
    o.w = f2bf(xc.w * tmc.w + xp.w * (1.f - tmc.w));
    *(ushort4*)(xm + i) = o;
}

// ---- bf16 MFMA GEMM: C[m,n] = sum_k A[m,k] * Bw[n,k]  (B^T form) ----
// 128x128 tile, BK=32, 4 waves (2x2), 64x64 per wave, 4x4 16x16x32 frags.
// MODE 0: plain f32 row-major [M][N] output.
// MODE 1: transformed bf16 TRANSPOSED [N][Mtot] output:
//         col <  C  -> exp(min(v,60))   (k path)
//         col < 2C  -> identity          (v path)
//         else      -> sigmoid(v)        (r path)
#define GLL16(GP, LP) __builtin_amdgcn_global_load_lds(                        \
    (__attribute__((address_space(1))) void*)(void*)(GP),                     \
    (__attribute__((address_space(3))) void*)(void*)(LP), 16, 0, 0)

template <int MODE>
__global__ __launch_bounds__(256) void gemm_bt(const unsigned short* __restrict__ A,
                                               const unsigned short* __restrict__ Bw,
                                               void* __restrict__ Cout,
                                               int N, int K, int Mtot) {
    __shared__ unsigned short lA[128 * 32];
    __shared__ unsigned short lB[128 * 32];
    const int tid  = threadIdx.x;
    const int lane = tid & 63;
    const int wid  = tid >> 6;
    const int wr   = wid >> 1, wc = wid & 1;
    const size_t m0 = (size_t)blockIdx.x * 128;
    const size_t n0 = (size_t)blockIdx.y * 128;

    const unsigned short* gA = A + (m0 + (size_t)(tid >> 2)) * K + ((tid & 3) << 3);
    const unsigned short* gB = Bw + (n0 + (size_t)(tid >> 2)) * K + ((tid & 3) << 3);
    char* sA = (char*)lA + tid * 16;
    char* sB = (char*)lB + tid * 16;

    f32x4 acc[4][4] = {};

    for (int k0 = 0; k0 < K; k0 += 32) {
        GLL16(gA + k0,             sA);
        GLL16(gA + k0 + 64 * K,    sA + 4096);
        GLL16(gB + k0,             sB);
        GLL16(gB + k0 + 64 * K,    sB + 4096);
        __syncthreads();

        const unsigned short* pA = lA + (wr * 64 + (lane & 15)) * 32 + ((lane >> 4) << 3);
        const unsigned short* pB = lB + (wc * 64 + (lane & 15)) * 32 + ((lane >> 4) << 3);
        bf16x8 a[4], b[4];
#pragma unroll
        for (int i = 0; i < 4; i++) {
            a[i] = __builtin_bit_cast(bf16x8, *(const short8*)(pA + i * 16 * 32));
            b[i] = __builtin_bit_cast(bf16x8, *(const short8*)(pB + i * 16 * 32));
        }
#pragma unroll
        for (int i = 0; i < 4; i++)
#pragma unroll
            for (int j = 0; j < 4; j++)
                acc[i][j] = __builtin_amdgcn_mfma_f32_16x16x32_bf16(a[i], b[j], acc[i][j], 0, 0, 0);
        __syncthreads();
    }

#pragma unroll
    for (int i = 0; i < 4; i++) {
#pragma unroll
        for (int j = 0; j < 4; j++) {
            size_t row = m0 + wr * 64 + i * 16 + ((lane >> 4) << 2);
            int    col = (int)n0 + wc * 64 + j * 16 + (lane & 15);
            if constexpr (MODE == 0) {
                float* Cp = (float*)Cout + row * (size_t)N + col;
#pragma unroll
                for (int q = 0; q < 4; q++) Cp[(size_t)q * N] = acc[i][j][q];
            } else {
                ushort4 o;
#pragma unroll
                for (int q = 0; q < 4; q++) {
                    float v = acc[i][j][q];
                    if (col < CDIM)            v = expf(fminf(v, 60.f));
                    else if (col >= 2 * CDIM)  v = 1.f / (1.f + expf(-v));
                    ((unsigned short*)&o)[q] = f2bf(v);
                }
                *(ushort4*)((unsigned short*)Cout + (size_t)col * Mtot + row) = o;
            }
        }
    }
}

// ---- chunked WKV scan on transposed bf16 projections ----
// kt layout: [3C][M] bf16; k rows already exp'd, r rows already sigmoid'd.
// Block: 16 channels x 16 chunks (L=48). tid = j*16 + cl.
__global__ __launch_bounds__(256) void wkv_scan_t(const unsigned short* __restrict__ kt,
                                                  const float* __restrict__ td,
                                                  const float* __restrict__ tf,
                                                  unsigned short* __restrict__ rwkv) {
    const int T = CTX_T, C = CDIM, M = MTOT;
    const int CW = 16, CH = 16, L = T / CH;   // 48 steps/chunk
    int bb = blockIdx.x >> 6;        // / (C/CW)
    int cg = blockIdx.x & 63;
    int cl = threadIdx.x & 15;
    int j  = threadIdx.x >> 4;
    int c  = cg * CW + cl;

    float ed    = expf(td[c]);
    float dec   = expf(-ed);
    float wself = expf(tf[c]);

    const unsigned short* rk = kt + (size_t)c * M + bb * T + j * L;
    const unsigned short* rv = rk + (size_t)C * M;
    const unsigned short* rr = rk + (size_t)2 * C * M;

    // phase 1: chunk-local sums (no carry)
    float A = 0.f, Bs = 0.f;
#pragma unroll
    for (int ib = 0; ib < L; ib += 8) {
        short8 kb = *(const short8*)(rk + ib);
        short8 vb = *(const short8*)(rv + ib);
#pragma unroll
        for (int e = 0; e < 8; e++) {
            float kk = bf2f((unsigned short)kb[e]);
            float vv = bf2f((unsigned short)vb[e]);
            A  = dec * A + kk * vv;
            Bs = dec * Bs + kk;
        }
    }

    __shared__ float sA[CH][CW], sB[CH][CW];
    sA[j][cl] = A; sB[j][cl] = Bs;
    __syncthreads();

    // phase 2: serial carry across the 16 chunks (16 threads, j==0 group)
    if (threadIdx.x < CW) {
        float dL = expf(-ed * (float)L);   // dec^L (thread cl owns channel cl here)
        float cA = 0.f, cB = 0.f;
#pragma unroll
        for (int q = 0; q < CH; q++) {
            float tA = sA[q][cl], tB = sB[q][cl];
            sA[q][cl] = cA; sB[q][cl] = cB;   // carry INTO chunk q
            cA = dL * cA + tA;
            cB = dL * cB + tB;
        }
    }
    __syncthreads();
    A = sA[j][cl]; Bs = sB[j][cl];

    // phase 3: scan with carry, emit sigmoid(r) * wkv / wk as bf16
    unsigned short* op = rwkv + ((size_t)(bb * T + j * L)) * C + c;
#pragma unroll
    for (int ib = 0; ib < L; ib += 8) {
        short8 kb = *(const short8*)(rk + ib);
        short8 vb = *(const short8*)(rv + ib);
        short8 rb = *(const short8*)(rr + ib);
#pragma unroll
        for (int e = 0; e < 8; e++) {
            float kk = bf2f((unsigned short)kb[e]);
            float vv = bf2f((unsigned short)vb[e]);
            float sg = bf2f((unsigned short)rb[e]);
            float kv  = kk * vv;
            float num = wself * kv + A;
            float den = wself * kk + Bs + 1e-9f;
            op[(size_t)(ib + e) * C] = f2bf(sg * num / den);
            A  = dec * A + kv;
            Bs = dec * Bs + kk;
        }
    }
}

extern "C" void kernel_launch(void* const* d_in, const int* in_sizes, int n_in,
                              void* d_out, int out_size, void* d_ws, size_t ws_size,
                              hipStream_t stream) {
    const float* x  = (const float*)d_in[0];
    const float* td = (const float*)d_in[1];
    const float* tf = (const float*)d_in[2];
    const float* tm = (const float*)d_in[3];
    const float* Wk = (const float*)d_in[4];
    const float* Wv = (const float*)d_in[5];
    const float* Wr = (const float*)d_in[6];
    const float* Wo = (const float*)d_in[7];
    float* out = (float*)d_out;

    const int B = BDIM, T = CTX_T, C = CDIM;
    const size_t M = (size_t)B * T;   // 6144

    size_t off = 0;
    auto carve = [&](size_t bytes) -> void* {
        void* p = (char*)d_ws + off;
        off += (bytes + 255) & ~(size_t)255;
        return p;
    };
    unsigned short* xm   = (unsigned short*)carve(M * C * 2);                 // bf16 mixed input
    unsigned short* wall = (unsigned short*)carve((size_t)4 * C * C * 2);     // [Wk;Wv;Wr;Wo] bf16
    unsigned short* kvrT = (unsigned short*)carve((size_t)3 * C * M * 2);     // [3C][M] bf16 transformed proj
    unsigned short* rwkv = (unsigned short*)carve(M * C * 2);                 // [M][C] bf16 gated output
    unsigned short* wkvr = wall;
    unsigned short* wo   = wall + (size_t)3 * C * C;

    cvt4<<<(4 * C * C) / 4 / 256, 256, 0, stream>>>(Wk, Wv, Wr, Wo, wall);

    const int total = (int)(M * C);
    mix_bf16<<<total / 4 / 256, 256, 0, stream>>>(x, tm, xm, total);

    dim3 g1((unsigned)(M / 128), (unsigned)(3 * C / 128));   // 48 x 24
    gemm_bt<1><<<g1, 256, 0, stream>>>(xm, wkvr, kvrT, 3 * C, C, (int)M);

    wkv_scan_t<<<B * (C / 16), 256, 0, stream>>>(kvrT, td, tf, rwkv);

    dim3 g2((unsigned)(M / 128), (unsigned)(C / 128));       // 48 x 8
    gemm_bt<0><<<g2, 256, 0, stream>>>(rwkv, wo, out, C, C, (int)M);
}